// Round 1
// 77.455 us; speedup vs baseline: 1.0298x; 1.0298x over previous
//
#include <hip/hip_runtime.h>

// Parzen-window histogram density, B=2, N=2, NUM_BINS=16, RADIUS=2, K=20.
//
// Reference semantics (verified absmax=0.0 in R7/R8): XLA-jitted f32, source
// association order, division strength-reduced to reciprocal-multiply:
//   bin_pos = fl32( a * cr32(1/bw_safe) ).
// Floor path BIT-EXACT (knife edge at 2/18 on every voxel):
//  * r = cr32(1/bws): v_rcp_f32 + f64-fma Newton + exact midpoint fixup.
//  * q = a * r: single native f32 mul (correctly rounded).
// Weights MUST follow the per-tap piecewise B-spline rounding (NOT the
// factorized basis polynomial on raw frac): R11's factorized form failed
// (absmax 0.152) on near-degenerate voxels.
//
// R(this): wave-uniform FAST PATH exploiting the N=2 structure. With two
// images, q ~= {2,18} everywhere, so fq in [1,18] and the two 4-tap windows
// (base in {1,16}) are disjoint. Then with e = q - fq (EXACT: Sterbenz) and
// u = 1 - e (EXACT: e lies on q's ulp grid >= 2^-23 since q >= 1), the four
// tap weights are {inner(e), inner(u), u^3/6, e^3/6} placed by j = fq-base,
// each SINGLE-branch and bitwise-faithful to bsplinef:
//   - every tap's ad value (e, 1-e, 1+e, 2-e) is the exactly-rounded value
//     of the reference's fl(q - bin) because e is exact on q's grid;
//   - inner(1) == outer(1) == 0x3E2AAAAB bitwise (all intermediates exact);
//   - outer(2) == +0 == reference's ad>=2 zero branch;
//   - outer's t = 2-ad is Sterbenz-exact (= u or e).
// The gather weight is ALWAYS the self tap inner(e), killing the 16-way
// predicated select. denom accumulation keeps the original interleaved
// order (wa_k, wb_k, k ascending) -> bitwise-identical sum.
// Degenerate voxels (c ~< 1e-6*|mn| pushes q out of range, or overlapping
// windows) fall back to the ORIGINAL verbatim general path, taken
// wave-uniformly via __all (expected ~0.03% of waves on this input).
//
// Decision rule for next round: ideal HBM traffic is 42.5 MB ~= 7 us; the
// timed dur includes ~47-52 us of harness poison fills (256 MiB
// fillBufferAligned @44.5 us seen in rocprof). If this -43% VALU cut does
// NOT move dur_us, the kernel is already small vs the fixed fills ->
// roofline reached.

typedef float f32x4 __attribute__((ext_vector_type(4)));

__device__ __forceinline__ float bsplinef(float d) {
    float ad = fabsf(d);
    float ad2 = ad * ad;
    float wi = (3.0f * ad2 * ad - 6.0f * ad2 + 4.0f) * (1.0f / 6.0f);
    float t = 2.0f - ad;
    float wo = (t * t * t) * (1.0f / 6.0f);
    float w = ad < 1.0f ? wi : wo;
    return ad < 2.0f ? w : 0.0f;
}

// inner-branch form: bitwise == bsplinef for ad in [0,1] (at ad==1 both
// branches give 0x3E2AAAAB: every intermediate is an exact small integer).
__device__ __forceinline__ float inner_w(float ad) {
    float ad2 = ad * ad;
    return (3.0f * ad2 * ad - 6.0f * ad2 + 4.0f) * (1.0f / 6.0f);
}
// outer-branch form on t = 2-ad: bitwise == bsplinef for ad in [1,2]
// (t in [0,1]; at ad==2 -> +0 == reference's zero branch).
__device__ __forceinline__ float outer_w(float t) {
    return (t * t * t) * (1.0f / 6.0f);
}

// exact correctly-rounded f32 reciprocal of b > 0 (no f64 division).
// UNCHANGED from the proven-exact version (knife-edge critical).
__device__ __forceinline__ float recip_cr32(float b) {
    double bd = (double)b;
    float u = __builtin_amdgcn_rcpf(b);           // within 1 ulp
    double ud = (double)u;
    double t = fma(-bd, ud, 1.0);                 // residual
    double g = fma(ud, t, ud);                    // ~2^-45 rel err
    float v = (float)g;                           // cr32 or one step off
    unsigned vi = __float_as_uint(v);
    float vn = __uint_as_float(vi + 1);
    float vd = __uint_as_float(vi - 1);
    double mp = 0.5 * ((double)v + (double)vn);   // exact midpoints
    double mm = 0.5 * ((double)v + (double)vd);
    if (mp * bd <= 1.0) v = vn;                   // true 1/b >= mp -> up
    else if (mm * bd > 1.0) v = vd;               // true 1/b <  mm -> down
    return v;
}

__device__ __forceinline__ void parzen_pair(float x0, float x1, float m0, float m1,
                                            float& o0, float& o1) {
    float mx = fmaxf(x0, x1);
    float mn = fminf(x0, x1);
    float c   = mx - mn;               // single cr32 sub
    float bw  = c * 0.0625f;           // exact (/16)
    float b2  = bw + bw;               // exact
    float pad = mn - b2;               // single cr32 sub
    float bws = fmaxf(bw, 1e-8f);
    float r   = recip_cr32(bws);       // cr32(1/bws)
    float a0  = x0 - pad;              // single cr32 sub
    float a1  = x1 - pad;
    float q0  = a0 * r;                // bin_pos = fl32(a*r)
    float q1  = a1 * r;

    int fq0 = (int)fminf(fmaxf(floorf(q0), 0.0f), 20.0f);
    int fq1 = (int)fminf(fmaxf(floorf(q1), 0.0f), 20.0f);
    int base0 = min(max(fq0, 2), 17) - 1;   // hist window {base..base+3}
    int base1 = min(max(fq1, 2), 17) - 1;

    // fast-path admissibility: fq in [1,18] (floor unclipped, q in [1,19),
    // e-exactness holds) and disjoint windows (no cross-window gather term).
    int db = base0 - base1;
    bool sane = ((unsigned)(fq0 - 1) <= 17u) && ((unsigned)(fq1 - 1) <= 17u)
                && (db >= 4 || db <= -4);

    float h0, h1, denom;
    if (__all((int)sane)) {
        // ---- fast path (wave-uniform; all bench voxels land here) ----
        int j0 = fq0 - base0;          // self-tap slot, in {0,1,2}
        int j1 = fq1 - base1;
        float e0 = q0 - (float)fq0;    // exact (Sterbenz)
        float e1 = q1 - (float)fq1;
        float u0 = 1.0f - e0;          // exact (e on q's ulp grid)
        float u1 = 1.0f - e1;
        float A0 = inner_w(e0), B0 = inner_w(u0);
        float C0 = outer_w(u0), D0 = outer_w(e0);   // = outer(1+e), outer(2-e)
        float A1 = inner_w(e1), B1 = inner_w(u1);
        float C1 = outer_w(u1), D1 = outer_w(e1);
        // slot vectors by j:  j=0:[A,B,D,0]  j=1:[C,A,B,D]  j=2:[0,C,A,B]
        bool c00 = (j0 == 0), c02 = (j0 == 2);
        float s00 = c00 ? A0 : (c02 ? 0.0f : C0);
        float s01 = c00 ? B0 : (c02 ? C0 : A0);
        float s02 = c00 ? D0 : (c02 ? A0 : B0);
        float s03 = c00 ? 0.0f : (c02 ? B0 : D0);
        bool c10 = (j1 == 0), c12 = (j1 == 2);
        float s10 = c10 ? A1 : (c12 ? 0.0f : C1);
        float s11 = c10 ? B1 : (c12 ? C1 : A1);
        float s12 = c10 ? D1 : (c12 ? A1 : B1);
        float s13 = c10 ? 0.0f : (c12 ? B1 : D1);
        // denom: EXACT original accumulation order (wa_k then wb_k, k asc)
        denom = s00;  denom += s10;
        denom += s01; denom += s11;
        denom += s02; denom += s12;
        denom += s03; denom += s13;
        // gather bin i = fq is the self tap -> weight is always inner(e);
        // cross-window term is structurally zero (disjointness checked).
        h0 = A0;
        h1 = A1;
    } else {
        // ---- general path: ORIGINAL verbatim (proven absmax=0.0) ----
        int i0 = min(fq0, 19);
        int i1 = min(fq1, 19);
        h0 = 0.0f; h1 = 0.0f; denom = 0.0f;
#pragma unroll
        for (int k = 0; k < 4; ++k) {
            float wa = bsplinef(q0 - (float)(base0 + k));
            float wb = bsplinef(q1 - (float)(base1 + k));
            denom += wa;
            denom += wb;
            h0 += (base0 + k == i0) ? wa : 0.0f;
            h0 += (base1 + k == i0) ? wb : 0.0f;
            h1 += (base0 + k == i1) ? wa : 0.0f;
            h1 += (base1 + k == i1) ? wb : 0.0f;
        }
    }

    float dc = fmaxf(denom, 1e-8f);
    float rd = __builtin_amdgcn_rcpf(dc);   // 1 ulp; denom==2.0 exactly on
    o0 = (m0 != 0.0f) ? (h0 * rd) : 0.0f;   // this input -> rcp exact
    o1 = (m1 != 0.0f) ? (h1 * rd) : 0.0f;
}

__global__ __launch_bounds__(256) void parzen_kernel(
    const float* __restrict__ img, const float* __restrict__ mask,
    float* __restrict__ out, int V) {
    const int V4 = V >> 2;
    int t = blockIdx.x * blockDim.x + threadIdx.x;
    if (t >= 2 * V4) return;               // B = 2
    int b = (t >= V4) ? 1 : 0;
    int v = (t - b * V4) << 2;

    size_t off0 = (size_t)(b * 2 + 0) * (size_t)V + (size_t)v;  // n = 0
    size_t off1 = (size_t)(b * 2 + 1) * (size_t)V + (size_t)v;  // n = 1

    // streaming data, zero reuse -> nontemporal loads (don't thrash L2)
    const f32x4 X0 = __builtin_nontemporal_load(reinterpret_cast<const f32x4*>(img  + off0));
    const f32x4 X1 = __builtin_nontemporal_load(reinterpret_cast<const f32x4*>(img  + off1));
    const f32x4 M0 = __builtin_nontemporal_load(reinterpret_cast<const f32x4*>(mask + off0));
    const f32x4 M1 = __builtin_nontemporal_load(reinterpret_cast<const f32x4*>(mask + off1));

    float a0, a1, b0, b1, c0, c1, d0, d1;
    parzen_pair(X0.x, X1.x, M0.x, M1.x, a0, a1);
    parzen_pair(X0.y, X1.y, M0.y, M1.y, b0, b1);
    parzen_pair(X0.z, X1.z, M0.z, M1.z, c0, c1);
    parzen_pair(X0.w, X1.w, M0.w, M1.w, d0, d1);

    f32x4 O0 = {a0, b0, c0, d0};
    f32x4 O1 = {a1, b1, c1, d1};
    __builtin_nontemporal_store(O0, reinterpret_cast<f32x4*>(out + off0));
    __builtin_nontemporal_store(O1, reinterpret_cast<f32x4*>(out + off1));
}

extern "C" void kernel_launch(void* const* d_in, const int* in_sizes, int n_in,
                              void* d_out, int out_size, void* d_ws, size_t ws_size,
                              hipStream_t stream) {
    const float* img  = (const float*)d_in[0];   // [2,2,1,96,96,96] f32
    const float* mask = (const float*)d_in[1];   // [2,2,96,96,96] f32
    float* out = (float*)d_out;                  // [2,2,96,96,96] f32

    int total = in_sizes[0];      // 4*V
    int V = total / 4;            // 884736 (divisible by 4)
    int threads = 2 * (V >> 2);
    int block = 256;
    int grid = (threads + block - 1) / block;
    parzen_kernel<<<grid, block, 0, stream>>>(img, mask, out, V);
}